// Round 13
// baseline (220.510 us; speedup 1.0000x reference)
//
#include <hip/hip_runtime.h>

#define NN 50000
#define NE 800000
#define INF 128
#define HID 64
#define HEADS 4
#define HD 256      // HEADS*HID
#define ACT 16
#define NEG_SLOPE 0.2f
#define CAP 64      // bucket capacity; P(deg>=64 | Poisson(16)) ~ 1e-18 per node

typedef short bf8 __attribute__((ext_vector_type(8)));   // 8 bf16 (bit pattern in shorts)
typedef float f4 __attribute__((ext_vector_type(4)));
typedef unsigned short u16;

__device__ __forceinline__ u16 f2bf(float f) {           // RNE fp32 -> bf16
    unsigned u = __builtin_bit_cast(unsigned, f);
    u += 0x7fffu + ((u >> 16) & 1u);
    return (u16)(u >> 16);
}
__device__ __forceinline__ float bf2f(u16 h) {
    return __builtin_bit_cast(float, (unsigned)h << 16);
}

// ================= device bodies =================================================

// ---- weight conversion to swizzled bf16 frag layout ----
__global__ __launch_bounds__(256) void convw_kernel(const float* __restrict__ fc_w,
    const float* __restrict__ a_w1, const float* __restrict__ a_w2,
    u16* __restrict__ Bsw1, u16* __restrict__ Bsw2, u16* __restrict__ w2sw)
{
    const int idx = blockIdx.x * 256 + threadIdx.x;
    if (idx < 32768) {                       // fc_w [128][256] -> 16ct x 4kc
        int j = idx & 7, l = (idx >> 3) & 63, q = idx >> 9;
        int kc = q & 3, ct = q >> 2;
        int k = kc * 32 + ((l >> 4) << 3) + j, col = (ct << 4) + (l & 15);
        Bsw1[idx] = f2bf(fc_w[k * 256 + col]);
    } else if (idx < 65536) {                // a_w1 [512][64] -> eff [256][128], 8ct x 8kc
        int o = idx - 32768;
        int j = o & 7, l = (o >> 3) & 63, q = o >> 9;
        int kc = q & 7, ct = q >> 3;
        int k = kc * 32 + ((l >> 4) << 3) + j, col = (ct << 4) + (l & 15);
        float v = (col < 64) ? a_w1[k * 64 + col] : a_w1[(256 + k) * 64 + (col - 64)];
        Bsw2[o] = f2bf(v);
    } else if (idx < 66560) {                // a_w2 [64][16] -> 1ct x 2kc
        int o = idx - 65536;
        int j = o & 7, l = (o >> 3) & 63, kc = o >> 9;
        int k = kc * 32 + ((l >> 4) << 3) + j, col = l & 15;
        w2sw[o] = f2bf(a_w2[k * 16 + col]);
    }
}

// ---- scatter into fixed-capacity buckets (no deg pass, no scan) ----
__device__ __forceinline__ void scatter_body(int bid, const int* __restrict__ src,
    const int* __restrict__ dst, int* __restrict__ cnt, u16* __restrict__ bucket)
{
    const int e = bid * 256 + threadIdx.x;   // range sized exactly NE
    const int d = dst[e];
    const int pos = atomicAdd(&cnt[d], 1);
    if (pos < CAP) bucket[(d << 6) + pos] = (u16)src[e];
}

// ---- gemm1 body: h_bf = bf16(x @ fc_w) + fused el/er; ct-split across waves ----
__device__ __forceinline__ void gemm1_body(int bid, const float* __restrict__ x,
    const u16* __restrict__ Bsw, const float* __restrict__ attn_l,
    const float* __restrict__ attn_r, u16* __restrict__ hb, float* __restrict__ elr)
{
    const int tid = threadIdx.x, w = tid >> 6, l = tid & 63;
    const int lk = l >> 4;
    const int rg = w & 1, ch = w >> 1;            // row-group, ct-half
    const int row = bid * 32 + rg * 16 + (l & 15);
    const int arow = row < NN ? row : NN - 1;
    const float* ap = x + (size_t)arow * INF + lk * 8;
    bf8 a[4];
#pragma unroll
    for (int kc = 0; kc < 4; ++kc) {
        float4 f0 = *(const float4*)(ap + kc * 32);
        float4 f1 = *(const float4*)(ap + kc * 32 + 4);
        bf8 t;
        t[0] = (short)f2bf(f0.x); t[1] = (short)f2bf(f0.y);
        t[2] = (short)f2bf(f0.z); t[3] = (short)f2bf(f0.w);
        t[4] = (short)f2bf(f1.x); t[5] = (short)f2bf(f1.y);
        t[6] = (short)f2bf(f1.z); t[7] = (short)f2bf(f1.w);
        a[kc] = t;
    }
    const bool ok = row < NN;
    float elp[2] = {0.f, 0.f}, erp[2] = {0.f, 0.f};
#pragma unroll
    for (int ci = 0; ci < 8; ci += 2) {
        const int ct = ch * 8 + ci;
        f4 acc0 = {0.f, 0.f, 0.f, 0.f}, acc1 = {0.f, 0.f, 0.f, 0.f};
#pragma unroll
        for (int kc = 0; kc < 4; ++kc) {
            bf8 b0 = *(const bf8*)(Bsw + (((ct * 4 + kc) * 64 + l) << 3));
            bf8 b1 = *(const bf8*)(Bsw + ((((ct + 1) * 4 + kc) * 64 + l) << 3));
            acc0 = __builtin_amdgcn_mfma_f32_16x16x32_bf16(b0, a[kc], acc0, 0, 0, 0);
            acc1 = __builtin_amdgcn_mfma_f32_16x16x32_bf16(b1, a[kc], acc1, 0, 0, 0);
        }
        const u16 r00 = f2bf(acc0[0]), r01 = f2bf(acc0[1]);
        const u16 r02 = f2bf(acc0[2]), r03 = f2bf(acc0[3]);
        const u16 r10 = f2bf(acc1[0]), r11 = f2bf(acc1[1]);
        const u16 r12 = f2bf(acc1[2]), r13 = f2bf(acc1[3]);
        if (ok) {
            *(uint2*)(hb + (size_t)row * HD + ct * 16 + lk * 4) =
                make_uint2((unsigned)r00 | ((unsigned)r01 << 16),
                           (unsigned)r02 | ((unsigned)r03 << 16));
            *(uint2*)(hb + (size_t)row * HD + (ct + 1) * 16 + lk * 4) =
                make_uint2((unsigned)r10 | ((unsigned)r11 << 16),
                           (unsigned)r12 | ((unsigned)r13 << 16));
        }
        const int hh = ci >> 2;                  // local head index within ct-half
        const float4 al0 = *(const float4*)(attn_l + ct * 16 + lk * 4);
        const float4 al1 = *(const float4*)(attn_l + (ct + 1) * 16 + lk * 4);
        const float4 ar0 = *(const float4*)(attn_r + ct * 16 + lk * 4);
        const float4 ar1 = *(const float4*)(attn_r + (ct + 1) * 16 + lk * 4);
        const float v00 = bf2f(r00), v01 = bf2f(r01), v02 = bf2f(r02), v03 = bf2f(r03);
        const float v10 = bf2f(r10), v11 = bf2f(r11), v12 = bf2f(r12), v13 = bf2f(r13);
        elp[hh] += v00 * al0.x + v01 * al0.y + v02 * al0.z + v03 * al0.w
                 + v10 * al1.x + v11 * al1.y + v12 * al1.z + v13 * al1.w;
        erp[hh] += v00 * ar0.x + v01 * ar0.y + v02 * ar0.z + v03 * ar0.w
                 + v10 * ar1.x + v11 * ar1.y + v12 * ar1.z + v13 * ar1.w;
    }
#pragma unroll
    for (int h = 0; h < 2; ++h) {
        elp[h] += __shfl_xor(elp[h], 16); elp[h] += __shfl_xor(elp[h], 32);
        erp[h] += __shfl_xor(erp[h], 16); erp[h] += __shfl_xor(erp[h], 32);
    }
    if (ok && lk == 0) {
        *(float2*)(elr + (size_t)row * 8 + ch * 2)     = make_float2(elp[0], elp[1]);
        *(float2*)(elr + (size_t)row * 8 + 4 + ch * 2) = make_float2(erp[0], erp[1]);
    }
}

// ---- fused: gemm1 (compute-bound) || bucket scatter (latency-bound) ----
__global__ __launch_bounds__(256) void k_g1scat(const float* __restrict__ x,
    const u16* __restrict__ Bsw1, const float* __restrict__ attn_l,
    const float* __restrict__ attn_r, u16* __restrict__ hb, float* __restrict__ elr,
    const int* __restrict__ src, const int* __restrict__ dst,
    int* __restrict__ cnt, u16* __restrict__ bucket)
{
    if (blockIdx.x < 1563) gemm1_body(blockIdx.x, x, Bsw1, attn_l, attn_r, hb, elr);
    else scatter_body(blockIdx.x - 1563, src, dst, cnt, bucket);
}

// ---- gemm2 body ----
__device__ __forceinline__ void gemm2_body(int bid, const u16* __restrict__ rstb,
    const u16* __restrict__ Bsw, const float* __restrict__ a_b1, u16* __restrict__ pqb)
{
    const int tid = threadIdx.x, w = tid >> 6, l = tid & 63;
    const int lk = l >> 4;
    const int row = bid * 64 + w * 16 + (l & 15);
    const int arow = row < NN ? row : NN - 1;
    const u16* ap = rstb + (size_t)arow * HD + lk * 8;
    bf8 a[8];
#pragma unroll
    for (int kc = 0; kc < 8; ++kc) a[kc] = *(const bf8*)(ap + kc * 32);
    const bool ok = row < NN;
#pragma unroll
    for (int ct = 0; ct < 8; ct += 2) {
        f4 acc0 = {0.f, 0.f, 0.f, 0.f}, acc1 = {0.f, 0.f, 0.f, 0.f};
#pragma unroll
        for (int kc = 0; kc < 8; ++kc) {
            bf8 b0 = *(const bf8*)(Bsw + (((ct * 8 + kc) * 64 + l) << 3));
            bf8 b1 = *(const bf8*)(Bsw + ((((ct + 1) * 8 + kc) * 64 + l) << 3));
            acc0 = __builtin_amdgcn_mfma_f32_16x16x32_bf16(b0, a[kc], acc0, 0, 0, 0);
            acc1 = __builtin_amdgcn_mfma_f32_16x16x32_bf16(b1, a[kc], acc1, 0, 0, 0);
        }
        if (ok) {
            const int c0 = ct * 16 + lk * 4;
            float v0[4] = {acc0[0], acc0[1], acc0[2], acc0[3]};
            float v1[4] = {acc1[0], acc1[1], acc1[2], acc1[3]};
            if (c0 >= 64) {
                float4 b = *(const float4*)(a_b1 + c0 - 64);
                v0[0] += b.x; v0[1] += b.y; v0[2] += b.z; v0[3] += b.w;
            }
            if (c0 + 16 >= 64) {
                float4 b = *(const float4*)(a_b1 + c0 + 16 - 64);
                v1[0] += b.x; v1[1] += b.y; v1[2] += b.z; v1[3] += b.w;
            }
            *(uint2*)(pqb + (size_t)row * 128 + c0) =
                make_uint2((unsigned)f2bf(v0[0]) | ((unsigned)f2bf(v0[1]) << 16),
                           (unsigned)f2bf(v0[2]) | ((unsigned)f2bf(v0[3]) << 16));
            *(uint2*)(pqb + (size_t)row * 128 + c0 + 16) =
                make_uint2((unsigned)f2bf(v1[0]) | ((unsigned)f2bf(v1[1]) << 16),
                           (unsigned)f2bf(v1[2]) | ((unsigned)f2bf(v1[3]) << 16));
        }
    }
}

// ---- mean stage 1 ----
__device__ __forceinline__ void mean_part_body(int mb, const u16* __restrict__ rstb,
                                               float* __restrict__ part)
{
    __shared__ float lds[8][256];
    const int t = threadIdx.x, g = t >> 5, f0 = (t & 31) * 8;
    float s[8] = {};
    for (int n = mb * 8 + g; n < NN; n += 128 * 8) {
        const uint4 u = *(const uint4*)(rstb + (size_t)n * HD + f0);
        s[0] += bf2f((u16)u.x); s[1] += bf2f((u16)(u.x >> 16));
        s[2] += bf2f((u16)u.y); s[3] += bf2f((u16)(u.y >> 16));
        s[4] += bf2f((u16)u.z); s[5] += bf2f((u16)(u.z >> 16));
        s[6] += bf2f((u16)u.w); s[7] += bf2f((u16)(u.w >> 16));
    }
#pragma unroll
    for (int j = 0; j < 8; ++j) lds[g][f0 + j] = s[j];
    __syncthreads();
    float tot = 0.f;
#pragma unroll
    for (int g2 = 0; g2 < 8; ++g2) tot += lds[g2][t];
    part[(size_t)mb * 256 + t] = tot;
}

// ---- mean stage 2 + critic head, single block ----
__device__ __forceinline__ void meanfin_critic_body(const float* __restrict__ part,
    const float* __restrict__ c_w1, const float* __restrict__ c_b1,
    const float* __restrict__ c_w2, const float* __restrict__ c_b2,
    float* __restrict__ outv)
{
    __shared__ float g[HD];
    __shared__ float t1[HID];
    const int t = threadIdx.x;
    float s = 0.f;
    for (int b = 0; b < 128; ++b) s += part[(size_t)b * 256 + t];
    g[t] = s * (1.0f / (float)NN);
    __syncthreads();
    if (t < HID) {
        float acc = c_b1[t];
        for (int c = 0; c < HD; ++c) acc += g[c] * c_w1[c * HID + t];
        t1[t] = fmaxf(acc, 0.f);
    }
    __syncthreads();
    if (t == 0) {
        float acc = c_b2[0];
        for (int j = 0; j < HID; ++j) acc += t1[j] * c_w2[j];
        outv[0] = acc;
    }
}

// ---- edge MLP via MFMA, original edge order (coalesced out writes) ----
__device__ __forceinline__ void edge_mlp_body(int bid, const int* __restrict__ src,
    const int* __restrict__ dst, const u16* __restrict__ pq,
    const u16* __restrict__ w2sw, const float* __restrict__ a_b2,
    float* __restrict__ out)
{
    const int tid = threadIdx.x, w = tid >> 6, l = tid & 63;
    const int lk = l >> 4;
    const int e = bid * 64 + w * 16 + (l & 15);
    const int s = src[e], d = dst[e];
    bf8 tf[2];
#pragma unroll
    for (int kc = 0; kc < 2; ++kc) {
        const int f = kc * 32 + lk * 8;
        bf8 pu = *(const bf8*)(pq + (size_t)s * 128 + f);
        bf8 qu = *(const bf8*)(pq + (size_t)d * 128 + 64 + f);
        bf8 t;
#pragma unroll
        for (int j = 0; j < 8; ++j) {
            float v = bf2f((u16)pu[j]) + bf2f((u16)qu[j]);   // b1 folded into q
            v = fmaxf(v, 0.f);
            t[j] = (short)f2bf(v);
        }
        tf[kc] = t;
    }
    const float4 b2v = *(const float4*)(a_b2 + lk * 4);
    f4 acc = {b2v.x, b2v.y, b2v.z, b2v.w};
    const bf8 w0 = *(const bf8*)(w2sw + (l << 3));
    const bf8 w1 = *(const bf8*)(w2sw + ((64 + l) << 3));
    acc = __builtin_amdgcn_mfma_f32_16x16x32_bf16(w0, tf[0], acc, 0, 0, 0);
    acc = __builtin_amdgcn_mfma_f32_16x16x32_bf16(w1, tf[1], acc, 0, 0, 0);
    __builtin_nontemporal_store(acc, (f4*)(out + (size_t)e * 16 + lk * 4));
}

// ================= kernels =======================================================

// ---- aggregation: one wave per node, bucket CSR, 8-deep gather (exact r9) ----
__global__ __launch_bounds__(256) void aggregate_kernel(
    const int* __restrict__ cnt, const u16* __restrict__ bucket,
    const float* __restrict__ elr, const u16* __restrict__ hb,
    const float* __restrict__ gat_bias, u16* __restrict__ rstb)
{
    __shared__ float exs[4][4][32];     // [wave][head][edge]
    __shared__ int ssrc[4][32];
    const int w = threadIdx.x >> 6, l = threadIdx.x & 63;
    const int d = blockIdx.x * 4 + w;
    const int end = min(cnt[d], CAP);
    const u16* bk = bucket + ((size_t)d << 6);
    const int h4 = l >> 4;              // head owning features l*4..l*4+3
    const int j0 = l >> 2, ph = l & 3;  // phase-1 task: edge j0/j0+16, head ph
    const float erd = elr[(size_t)d * 8 + 4 + ph];
    float acc0 = 0.f, acc1 = 0.f, acc2 = 0.f, acc3 = 0.f, zsum = 0.f;
    for (int cs = 0; cs < end; cs += 32) {
        const int n = min(32, end - cs);
        __builtin_amdgcn_wave_barrier();
        if (j0 < n) {
            const int s = bk[cs + j0];
            if (ph == 0) ssrc[w][j0] = s;
            float xv = elr[(size_t)s * 8 + ph] + erd;
            xv = xv > 0.f ? xv : NEG_SLOPE * xv;
            exs[w][ph][j0] = __expf(xv);
        }
        if (j0 + 16 < n) {
            const int s = bk[cs + j0 + 16];
            if (ph == 0) ssrc[w][j0 + 16] = s;
            float xv = elr[(size_t)s * 8 + ph] + erd;
            xv = xv > 0.f ? xv : NEG_SLOPE * xv;
            exs[w][ph][j0 + 16] = __expf(xv);
        }
        __builtin_amdgcn_wave_barrier();
        int jj = 0;
        for (; jj + 8 <= n; jj += 8) {
            float ev[8]; int sv[8]; uint2 uu[8];
            *(f4*)&ev[0] = *(const f4*)&exs[w][h4][jj];
            *(f4*)&ev[4] = *(const f4*)&exs[w][h4][jj + 4];
            *(int4*)&sv[0] = *(const int4*)&ssrc[w][jj];
            *(int4*)&sv[4] = *(const int4*)&ssrc[w][jj + 4];
#pragma unroll
            for (int q = 0; q < 8; ++q) {
                const int s = __builtin_amdgcn_readfirstlane(sv[q]);
                uu[q] = *(const uint2*)(hb + (size_t)s * HD + l * 4);
            }
#pragma unroll
            for (int q = 0; q < 8; ++q) {
                zsum += ev[q];
                acc0 += ev[q] * bf2f((u16)uu[q].x);
                acc1 += ev[q] * bf2f((u16)(uu[q].x >> 16));
                acc2 += ev[q] * bf2f((u16)uu[q].y);
                acc3 += ev[q] * bf2f((u16)(uu[q].y >> 16));
            }
        }
        for (; jj < n; ++jj) {
            const float e = exs[w][h4][jj];
            const int s2 = __builtin_amdgcn_readfirstlane(ssrc[w][jj]);
            const uint2 u = *(const uint2*)(hb + (size_t)s2 * HD + l * 4);
            zsum += e;
            acc0 += e * bf2f((u16)u.x);
            acc1 += e * bf2f((u16)(u.x >> 16));
            acc2 += e * bf2f((u16)u.y);
            acc3 += e * bf2f((u16)(u.y >> 16));
        }
    }
    const float inv = (end > 0) ? 1.f / zsum : 0.f;
    const float4 gb = *(const float4*)(gat_bias + l * 4);
    float v0 = acc0 * inv + gb.x;
    float v1 = acc1 * inv + gb.y;
    float v2 = acc2 * inv + gb.z;
    float v3 = acc3 * inv + gb.w;
    v0 = v0 > 0.f ? v0 : (__expf(v0) - 1.f);   // elu: exp-1 ok under bf16 rounding
    v1 = v1 > 0.f ? v1 : (__expf(v1) - 1.f);
    v2 = v2 > 0.f ? v2 : (__expf(v2) - 1.f);
    v3 = v3 > 0.f ? v3 : (__expf(v3) - 1.f);
    *(uint2*)(rstb + (size_t)d * HD + l * 4) =
        make_uint2((unsigned)f2bf(v0) | ((unsigned)f2bf(v1) << 16),
                   (unsigned)f2bf(v2) | ((unsigned)f2bf(v3) << 16));
}

__global__ __launch_bounds__(256) void k_g2mean(const u16* __restrict__ rstb,
    const u16* __restrict__ Bsw2, const float* __restrict__ a_b1,
    u16* __restrict__ pqb, float* __restrict__ part)
{
    if (blockIdx.x < 782) gemm2_body(blockIdx.x, rstb, Bsw2, a_b1, pqb);
    else mean_part_body(blockIdx.x - 782, rstb, part);
}

__global__ __launch_bounds__(256) void k_mlpfin(const int* __restrict__ src,
    const int* __restrict__ dst, const u16* __restrict__ pqb,
    const u16* __restrict__ w2sw, const float* __restrict__ a_b2,
    float* __restrict__ out, const float* __restrict__ part,
    const float* __restrict__ c_w1, const float* __restrict__ c_b1,
    const float* __restrict__ c_w2, const float* __restrict__ c_b2,
    float* __restrict__ outv)
{
    if (blockIdx.x < 12500) edge_mlp_body(blockIdx.x, src, dst, pqb, w2sw, a_b2, out);
    else meanfin_critic_body(part, c_w1, c_b1, c_w2, c_b2, outv);
}

extern "C" void kernel_launch(void* const* d_in, const int* in_sizes, int n_in,
                              void* d_out, int out_size, void* d_ws, size_t ws_size,
                              hipStream_t stream)
{
    const float* x      = (const float*)d_in[0];
    const int*   src    = (const int*)d_in[1];
    const int*   dst    = (const int*)d_in[2];
    const float* fc_w   = (const float*)d_in[3];
    const float* attn_l = (const float*)d_in[4];
    const float* attn_r = (const float*)d_in[5];
    const float* gat_b  = (const float*)d_in[6];
    const float* a_w1   = (const float*)d_in[7];
    const float* a_b1   = (const float*)d_in[8];
    const float* a_w2   = (const float*)d_in[9];
    const float* a_b2   = (const float*)d_in[10];
    const float* c_w1   = (const float*)d_in[11];
    const float* c_b1   = (const float*)d_in[12];
    const float* c_w2   = (const float*)d_in[13];
    const float* c_b2   = (const float*)d_in[14];
    float* out = (float*)d_out;

    char* p = (char*)d_ws;
    u16* hb     = (u16*)p;   p += (size_t)NN * HD * 2;     // 25.6 MB
    u16* rstb   = (u16*)p;   p += (size_t)NN * HD * 2;     // 25.6 MB
    u16* pqb    = (u16*)p;   p += (size_t)NN * 128 * 2;    // 12.8 MB
    float* elr  = (float*)p; p += (size_t)NN * 8 * 4;      //  1.6 MB
    float* part = (float*)p; p += 128 * 256 * 4;           // mean partials
    u16* Bsw1   = (u16*)p;   p += 65536;
    u16* Bsw2   = (u16*)p;   p += 65536;
    u16* w2sw   = (u16*)p;   p += 2048;
    int* cnt    = (int*)p;   p += (size_t)NN * 4;          // bucket counters
    u16* bucket = (u16*)p;   p += (size_t)NN * CAP * 2;    //  6.4 MB

    hipMemsetAsync(cnt, 0, (size_t)NN * 4, stream);

    dim3 blk(256);
    // L1: weight swizzle (small, must precede gemm1/gemm2/mlp)
    convw_kernel<<<dim3(260), blk, 0, stream>>>(fc_w, a_w1, a_w2, Bsw1, Bsw2, w2sw);
    // L2: gemm1 (1563 blocks, compute-bound) || bucket scatter (3125, latency-bound)
    k_g1scat<<<dim3(1563 + 3125), blk, 0, stream>>>(x, Bsw1, attn_l, attn_r, hb, elr,
                                                    src, dst, cnt, bucket);
    // L3: gather-aggregate from buckets (r9 kernel — at its EA roofline)
    aggregate_kernel<<<dim3(NN / 4), blk, 0, stream>>>(cnt, bucket, elr, hb, gat_b, rstb);
    // L4: pq = bf16(rst @ [w1_top|w1_bot] + [0|b1])  ||  mean stage 1
    k_g2mean<<<dim3(782 + 128), blk, 0, stream>>>(rstb, Bsw2, a_b1, pqb, part);
    // L5: per-edge actor MLP || mean stage 2 + critic head (fused, one block)
    k_mlpfin<<<dim3(12500 + 1), blk, 0, stream>>>(src, dst, pqb, w2sw, a_b2, out, part,
                                                  c_w1, c_b1, c_w2, c_b2,
                                                  out + (size_t)NE * ACT);
}

// Round 14
// 207.921 us; speedup vs baseline: 1.0605x; 1.0605x over previous
//
#include <hip/hip_runtime.h>

#define NN 50000
#define NE 800000
#define INF 128
#define HID 64
#define HEADS 4
#define HD 256      // HEADS*HID
#define ACT 16
#define NEG_SLOPE 0.2f
#define CAP 64      // bucket capacity; P(deg>=64 | Poisson(16)) ~ 1e-18 per node

typedef short bf8 __attribute__((ext_vector_type(8)));   // 8 bf16 (bit pattern in shorts)
typedef float f4 __attribute__((ext_vector_type(4)));
typedef unsigned short u16;

__device__ __forceinline__ u16 f2bf(float f) {           // RNE fp32 -> bf16
    unsigned u = __builtin_bit_cast(unsigned, f);
    u += 0x7fffu + ((u >> 16) & 1u);
    return (u16)(u >> 16);
}
__device__ __forceinline__ float bf2f(u16 h) {
    return __builtin_bit_cast(float, (unsigned)h << 16);
}

// ================= device bodies =================================================

// ---- weight conversion to swizzled bf16 frag layout ----
__device__ __forceinline__ void convw_body(int bid, const float* __restrict__ fc_w,
    const float* __restrict__ a_w1, const float* __restrict__ a_w2,
    u16* __restrict__ Bsw1, u16* __restrict__ Bsw2, u16* __restrict__ w2sw)
{
    const int idx = bid * 256 + threadIdx.x;
    if (idx < 32768) {                       // fc_w [128][256] -> 16ct x 4kc
        int j = idx & 7, l = (idx >> 3) & 63, q = idx >> 9;
        int kc = q & 3, ct = q >> 2;
        int k = kc * 32 + ((l >> 4) << 3) + j, col = (ct << 4) + (l & 15);
        Bsw1[idx] = f2bf(fc_w[k * 256 + col]);
    } else if (idx < 65536) {                // a_w1 [512][64] -> eff [256][128], 8ct x 8kc
        int o = idx - 32768;
        int j = o & 7, l = (o >> 3) & 63, q = o >> 9;
        int kc = q & 7, ct = q >> 3;
        int k = kc * 32 + ((l >> 4) << 3) + j, col = (ct << 4) + (l & 15);
        float v = (col < 64) ? a_w1[k * 64 + col] : a_w1[(256 + k) * 64 + (col - 64)];
        Bsw2[o] = f2bf(v);
    } else if (idx < 66560) {                // a_w2 [64][16] -> 1ct x 2kc
        int o = idx - 65536;
        int j = o & 7, l = (o >> 3) & 63, kc = o >> 9;
        int k = kc * 32 + ((l >> 4) << 3) + j, col = l & 15;
        w2sw[o] = f2bf(a_w2[k * 16 + col]);
    }
}

// ---- scatter into fixed-capacity buckets (no deg pass, no scan) ----
__device__ __forceinline__ void scatter_body(int bid, const int* __restrict__ src,
    const int* __restrict__ dst, int* __restrict__ cnt, u16* __restrict__ bucket)
{
    const int e = bid * 256 + threadIdx.x;   // range sized exactly NE
    const int d = dst[e];
    const int pos = atomicAdd(&cnt[d], 1);
    if (pos < CAP) bucket[(d << 6) + pos] = (u16)src[e];
}

// ---- gemm2 body ----
__device__ __forceinline__ void gemm2_body(int bid, const u16* __restrict__ rstb,
    const u16* __restrict__ Bsw, const float* __restrict__ a_b1, u16* __restrict__ pqb)
{
    const int tid = threadIdx.x, w = tid >> 6, l = tid & 63;
    const int lk = l >> 4;
    const int row = bid * 64 + w * 16 + (l & 15);
    const int arow = row < NN ? row : NN - 1;
    const u16* ap = rstb + (size_t)arow * HD + lk * 8;
    bf8 a[8];
#pragma unroll
    for (int kc = 0; kc < 8; ++kc) a[kc] = *(const bf8*)(ap + kc * 32);
    const bool ok = row < NN;
#pragma unroll
    for (int ct = 0; ct < 8; ct += 2) {
        f4 acc0 = {0.f, 0.f, 0.f, 0.f}, acc1 = {0.f, 0.f, 0.f, 0.f};
#pragma unroll
        for (int kc = 0; kc < 8; ++kc) {
            bf8 b0 = *(const bf8*)(Bsw + (((ct * 8 + kc) * 64 + l) << 3));
            bf8 b1 = *(const bf8*)(Bsw + ((((ct + 1) * 8 + kc) * 64 + l) << 3));
            acc0 = __builtin_amdgcn_mfma_f32_16x16x32_bf16(b0, a[kc], acc0, 0, 0, 0);
            acc1 = __builtin_amdgcn_mfma_f32_16x16x32_bf16(b1, a[kc], acc1, 0, 0, 0);
        }
        if (ok) {
            const int c0 = ct * 16 + lk * 4;
            float v0[4] = {acc0[0], acc0[1], acc0[2], acc0[3]};
            float v1[4] = {acc1[0], acc1[1], acc1[2], acc1[3]};
            if (c0 >= 64) {
                float4 b = *(const float4*)(a_b1 + c0 - 64);
                v0[0] += b.x; v0[1] += b.y; v0[2] += b.z; v0[3] += b.w;
            }
            if (c0 + 16 >= 64) {
                float4 b = *(const float4*)(a_b1 + c0 + 16 - 64);
                v1[0] += b.x; v1[1] += b.y; v1[2] += b.z; v1[3] += b.w;
            }
            *(uint2*)(pqb + (size_t)row * 128 + c0) =
                make_uint2((unsigned)f2bf(v0[0]) | ((unsigned)f2bf(v0[1]) << 16),
                           (unsigned)f2bf(v0[2]) | ((unsigned)f2bf(v0[3]) << 16));
            *(uint2*)(pqb + (size_t)row * 128 + c0 + 16) =
                make_uint2((unsigned)f2bf(v1[0]) | ((unsigned)f2bf(v1[1]) << 16),
                           (unsigned)f2bf(v1[2]) | ((unsigned)f2bf(v1[3]) << 16));
        }
    }
}

// ---- mean stage 1 ----
__device__ __forceinline__ void mean_part_body(int mb, const u16* __restrict__ rstb,
                                               float* __restrict__ part)
{
    __shared__ float lds[8][256];
    const int t = threadIdx.x, g = t >> 5, f0 = (t & 31) * 8;
    float s[8] = {};
    for (int n = mb * 8 + g; n < NN; n += 128 * 8) {
        const uint4 u = *(const uint4*)(rstb + (size_t)n * HD + f0);
        s[0] += bf2f((u16)u.x); s[1] += bf2f((u16)(u.x >> 16));
        s[2] += bf2f((u16)u.y); s[3] += bf2f((u16)(u.y >> 16));
        s[4] += bf2f((u16)u.z); s[5] += bf2f((u16)(u.z >> 16));
        s[6] += bf2f((u16)u.w); s[7] += bf2f((u16)(u.w >> 16));
    }
#pragma unroll
    for (int j = 0; j < 8; ++j) lds[g][f0 + j] = s[j];
    __syncthreads();
    float tot = 0.f;
#pragma unroll
    for (int g2 = 0; g2 < 8; ++g2) tot += lds[g2][t];
    part[(size_t)mb * 256 + t] = tot;
}

// ---- mean stage 2 + critic head, single block ----
__device__ __forceinline__ void meanfin_critic_body(const float* __restrict__ part,
    const float* __restrict__ c_w1, const float* __restrict__ c_b1,
    const float* __restrict__ c_w2, const float* __restrict__ c_b2,
    float* __restrict__ outv)
{
    __shared__ float g[HD];
    __shared__ float t1[HID];
    const int t = threadIdx.x;
    float s = 0.f;
    for (int b = 0; b < 128; ++b) s += part[(size_t)b * 256 + t];
    g[t] = s * (1.0f / (float)NN);
    __syncthreads();
    if (t < HID) {
        float acc = c_b1[t];
        for (int c = 0; c < HD; ++c) acc += g[c] * c_w1[c * HID + t];
        t1[t] = fmaxf(acc, 0.f);
    }
    __syncthreads();
    if (t == 0) {
        float acc = c_b2[0];
        for (int j = 0; j < HID; ++j) acc += t1[j] * c_w2[j];
        outv[0] = acc;
    }
}

// ---- edge MLP via MFMA, original edge order (coalesced out writes) ----
__device__ __forceinline__ void edge_mlp_body(int bid, const int* __restrict__ src,
    const int* __restrict__ dst, const u16* __restrict__ pq,
    const u16* __restrict__ w2sw, const float* __restrict__ a_b2,
    float* __restrict__ out)
{
    const int tid = threadIdx.x, w = tid >> 6, l = tid & 63;
    const int lk = l >> 4;
    const int e = bid * 64 + w * 16 + (l & 15);
    const int s = src[e], d = dst[e];
    bf8 tf[2];
#pragma unroll
    for (int kc = 0; kc < 2; ++kc) {
        const int f = kc * 32 + lk * 8;
        bf8 pu = *(const bf8*)(pq + (size_t)s * 128 + f);
        bf8 qu = *(const bf8*)(pq + (size_t)d * 128 + 64 + f);
        bf8 t;
#pragma unroll
        for (int j = 0; j < 8; ++j) {
            float v = bf2f((u16)pu[j]) + bf2f((u16)qu[j]);   // b1 folded into q
            v = fmaxf(v, 0.f);
            t[j] = (short)f2bf(v);
        }
        tf[kc] = t;
    }
    const float4 b2v = *(const float4*)(a_b2 + lk * 4);
    f4 acc = {b2v.x, b2v.y, b2v.z, b2v.w};
    const bf8 w0 = *(const bf8*)(w2sw + (l << 3));
    const bf8 w1 = *(const bf8*)(w2sw + ((64 + l) << 3));
    acc = __builtin_amdgcn_mfma_f32_16x16x32_bf16(w0, tf[0], acc, 0, 0, 0);
    acc = __builtin_amdgcn_mfma_f32_16x16x32_bf16(w1, tf[1], acc, 0, 0, 0);
    __builtin_nontemporal_store(acc, (f4*)(out + (size_t)e * 16 + lk * 4));
}

// ================= kernels =======================================================

// ---- scatter (buckets) + weight swizzle, both low-VGPR, one launch (r9) ----
__global__ __launch_bounds__(256) void k_scatconv(const int* __restrict__ src,
    const int* __restrict__ dst, int* __restrict__ cnt, u16* __restrict__ bucket,
    const float* __restrict__ fc_w, const float* __restrict__ a_w1,
    const float* __restrict__ a_w2, u16* __restrict__ Bsw1,
    u16* __restrict__ Bsw2, u16* __restrict__ w2sw)
{
    if (blockIdx.x < 3125) scatter_body(blockIdx.x, src, dst, cnt, bucket);
    else convw_body(blockIdx.x - 3125, fc_w, a_w1, a_w2, Bsw1, Bsw2, w2sw);
}

// ---- gemm1: h_bf = bf16(x @ fc_w) + fused el/er; ct-split across waves (r9) ----
__global__ __launch_bounds__(256) void gemm1_kernel(const float* __restrict__ x,
    const u16* __restrict__ Bsw, const float* __restrict__ attn_l,
    const float* __restrict__ attn_r, u16* __restrict__ hb, float* __restrict__ elr)
{
    const int tid = threadIdx.x, w = tid >> 6, l = tid & 63;
    const int lk = l >> 4;
    const int rg = w & 1, ch = w >> 1;            // row-group, ct-half
    const int row = blockIdx.x * 32 + rg * 16 + (l & 15);
    const int arow = row < NN ? row : NN - 1;
    const float* ap = x + (size_t)arow * INF + lk * 8;
    bf8 a[4];
#pragma unroll
    for (int kc = 0; kc < 4; ++kc) {
        float4 f0 = *(const float4*)(ap + kc * 32);
        float4 f1 = *(const float4*)(ap + kc * 32 + 4);
        bf8 t;
        t[0] = (short)f2bf(f0.x); t[1] = (short)f2bf(f0.y);
        t[2] = (short)f2bf(f0.z); t[3] = (short)f2bf(f0.w);
        t[4] = (short)f2bf(f1.x); t[5] = (short)f2bf(f1.y);
        t[6] = (short)f2bf(f1.z); t[7] = (short)f2bf(f1.w);
        a[kc] = t;
    }
    const bool ok = row < NN;
    float elp[2] = {0.f, 0.f}, erp[2] = {0.f, 0.f};
#pragma unroll
    for (int ci = 0; ci < 8; ci += 2) {
        const int ct = ch * 8 + ci;
        f4 acc0 = {0.f, 0.f, 0.f, 0.f}, acc1 = {0.f, 0.f, 0.f, 0.f};
#pragma unroll
        for (int kc = 0; kc < 4; ++kc) {
            bf8 b0 = *(const bf8*)(Bsw + (((ct * 4 + kc) * 64 + l) << 3));
            bf8 b1 = *(const bf8*)(Bsw + ((((ct + 1) * 4 + kc) * 64 + l) << 3));
            acc0 = __builtin_amdgcn_mfma_f32_16x16x32_bf16(b0, a[kc], acc0, 0, 0, 0);
            acc1 = __builtin_amdgcn_mfma_f32_16x16x32_bf16(b1, a[kc], acc1, 0, 0, 0);
        }
        const u16 r00 = f2bf(acc0[0]), r01 = f2bf(acc0[1]);
        const u16 r02 = f2bf(acc0[2]), r03 = f2bf(acc0[3]);
        const u16 r10 = f2bf(acc1[0]), r11 = f2bf(acc1[1]);
        const u16 r12 = f2bf(acc1[2]), r13 = f2bf(acc1[3]);
        if (ok) {
            *(uint2*)(hb + (size_t)row * HD + ct * 16 + lk * 4) =
                make_uint2((unsigned)r00 | ((unsigned)r01 << 16),
                           (unsigned)r02 | ((unsigned)r03 << 16));
            *(uint2*)(hb + (size_t)row * HD + (ct + 1) * 16 + lk * 4) =
                make_uint2((unsigned)r10 | ((unsigned)r11 << 16),
                           (unsigned)r12 | ((unsigned)r13 << 16));
        }
        const int hh = ci >> 2;                  // local head index within ct-half
        const float4 al0 = *(const float4*)(attn_l + ct * 16 + lk * 4);
        const float4 al1 = *(const float4*)(attn_l + (ct + 1) * 16 + lk * 4);
        const float4 ar0 = *(const float4*)(attn_r + ct * 16 + lk * 4);
        const float4 ar1 = *(const float4*)(attn_r + (ct + 1) * 16 + lk * 4);
        const float v00 = bf2f(r00), v01 = bf2f(r01), v02 = bf2f(r02), v03 = bf2f(r03);
        const float v10 = bf2f(r10), v11 = bf2f(r11), v12 = bf2f(r12), v13 = bf2f(r13);
        elp[hh] += v00 * al0.x + v01 * al0.y + v02 * al0.z + v03 * al0.w
                 + v10 * al1.x + v11 * al1.y + v12 * al1.z + v13 * al1.w;
        erp[hh] += v00 * ar0.x + v01 * ar0.y + v02 * ar0.z + v03 * ar0.w
                 + v10 * ar1.x + v11 * ar1.y + v12 * ar1.z + v13 * ar1.w;
    }
#pragma unroll
    for (int h = 0; h < 2; ++h) {
        elp[h] += __shfl_xor(elp[h], 16); elp[h] += __shfl_xor(elp[h], 32);
        erp[h] += __shfl_xor(erp[h], 16); erp[h] += __shfl_xor(erp[h], 32);
    }
    if (ok && lk == 0) {
        *(float2*)(elr + (size_t)row * 8 + ch * 2)     = make_float2(elp[0], elp[1]);
        *(float2*)(elr + (size_t)row * 8 + 4 + ch * 2) = make_float2(erp[0], erp[1]);
    }
}

// ---- aggregation: one wave per node, bucket CSR, 8-deep gather (exact r9) ----
__global__ __launch_bounds__(256) void aggregate_kernel(
    const int* __restrict__ cnt, const u16* __restrict__ bucket,
    const float* __restrict__ elr, const u16* __restrict__ hb,
    const float* __restrict__ gat_bias, u16* __restrict__ rstb)
{
    __shared__ float exs[4][4][32];     // [wave][head][edge]
    __shared__ int ssrc[4][32];
    const int w = threadIdx.x >> 6, l = threadIdx.x & 63;
    const int d = blockIdx.x * 4 + w;
    const int end = min(cnt[d], CAP);
    const u16* bk = bucket + ((size_t)d << 6);
    const int h4 = l >> 4;              // head owning features l*4..l*4+3
    const int j0 = l >> 2, ph = l & 3;  // phase-1 task: edge j0/j0+16, head ph
    const float erd = elr[(size_t)d * 8 + 4 + ph];
    float acc0 = 0.f, acc1 = 0.f, acc2 = 0.f, acc3 = 0.f, zsum = 0.f;
    for (int cs = 0; cs < end; cs += 32) {
        const int n = min(32, end - cs);
        __builtin_amdgcn_wave_barrier();
        if (j0 < n) {
            const int s = bk[cs + j0];
            if (ph == 0) ssrc[w][j0] = s;
            float xv = elr[(size_t)s * 8 + ph] + erd;
            xv = xv > 0.f ? xv : NEG_SLOPE * xv;
            exs[w][ph][j0] = __expf(xv);
        }
        if (j0 + 16 < n) {
            const int s = bk[cs + j0 + 16];
            if (ph == 0) ssrc[w][j0 + 16] = s;
            float xv = elr[(size_t)s * 8 + ph] + erd;
            xv = xv > 0.f ? xv : NEG_SLOPE * xv;
            exs[w][ph][j0 + 16] = __expf(xv);
        }
        __builtin_amdgcn_wave_barrier();
        int jj = 0;
        for (; jj + 8 <= n; jj += 8) {
            float ev[8]; int sv[8]; uint2 uu[8];
            *(f4*)&ev[0] = *(const f4*)&exs[w][h4][jj];
            *(f4*)&ev[4] = *(const f4*)&exs[w][h4][jj + 4];
            *(int4*)&sv[0] = *(const int4*)&ssrc[w][jj];
            *(int4*)&sv[4] = *(const int4*)&ssrc[w][jj + 4];
#pragma unroll
            for (int q = 0; q < 8; ++q) {
                const int s = __builtin_amdgcn_readfirstlane(sv[q]);
                uu[q] = *(const uint2*)(hb + (size_t)s * HD + l * 4);
            }
#pragma unroll
            for (int q = 0; q < 8; ++q) {
                zsum += ev[q];
                acc0 += ev[q] * bf2f((u16)uu[q].x);
                acc1 += ev[q] * bf2f((u16)(uu[q].x >> 16));
                acc2 += ev[q] * bf2f((u16)uu[q].y);
                acc3 += ev[q] * bf2f((u16)(uu[q].y >> 16));
            }
        }
        for (; jj < n; ++jj) {
            const float e = exs[w][h4][jj];
            const int s2 = __builtin_amdgcn_readfirstlane(ssrc[w][jj]);
            const uint2 u = *(const uint2*)(hb + (size_t)s2 * HD + l * 4);
            zsum += e;
            acc0 += e * bf2f((u16)u.x);
            acc1 += e * bf2f((u16)(u.x >> 16));
            acc2 += e * bf2f((u16)u.y);
            acc3 += e * bf2f((u16)(u.y >> 16));
        }
    }
    const float inv = (end > 0) ? 1.f / zsum : 0.f;
    const float4 gb = *(const float4*)(gat_bias + l * 4);
    float v0 = acc0 * inv + gb.x;
    float v1 = acc1 * inv + gb.y;
    float v2 = acc2 * inv + gb.z;
    float v3 = acc3 * inv + gb.w;
    v0 = v0 > 0.f ? v0 : (__expf(v0) - 1.f);   // elu: exp-1 ok under bf16 rounding
    v1 = v1 > 0.f ? v1 : (__expf(v1) - 1.f);
    v2 = v2 > 0.f ? v2 : (__expf(v2) - 1.f);
    v3 = v3 > 0.f ? v3 : (__expf(v3) - 1.f);
    *(uint2*)(rstb + (size_t)d * HD + l * 4) =
        make_uint2((unsigned)f2bf(v0) | ((unsigned)f2bf(v1) << 16),
                   (unsigned)f2bf(v2) | ((unsigned)f2bf(v3) << 16));
}

__global__ __launch_bounds__(256) void k_g2mean(const u16* __restrict__ rstb,
    const u16* __restrict__ Bsw2, const float* __restrict__ a_b1,
    u16* __restrict__ pqb, float* __restrict__ part)
{
    if (blockIdx.x < 782) gemm2_body(blockIdx.x, rstb, Bsw2, a_b1, pqb);
    else mean_part_body(blockIdx.x - 782, rstb, part);
}

__global__ __launch_bounds__(256) void k_mlpfin(const int* __restrict__ src,
    const int* __restrict__ dst, const u16* __restrict__ pqb,
    const u16* __restrict__ w2sw, const float* __restrict__ a_b2,
    float* __restrict__ out, const float* __restrict__ part,
    const float* __restrict__ c_w1, const float* __restrict__ c_b1,
    const float* __restrict__ c_w2, const float* __restrict__ c_b2,
    float* __restrict__ outv)
{
    if (blockIdx.x < 12500) edge_mlp_body(blockIdx.x, src, dst, pqb, w2sw, a_b2, out);
    else meanfin_critic_body(part, c_w1, c_b1, c_w2, c_b2, outv);
}

extern "C" void kernel_launch(void* const* d_in, const int* in_sizes, int n_in,
                              void* d_out, int out_size, void* d_ws, size_t ws_size,
                              hipStream_t stream)
{
    const float* x      = (const float*)d_in[0];
    const int*   src    = (const int*)d_in[1];
    const int*   dst    = (const int*)d_in[2];
    const float* fc_w   = (const float*)d_in[3];
    const float* attn_l = (const float*)d_in[4];
    const float* attn_r = (const float*)d_in[5];
    const float* gat_b  = (const float*)d_in[6];
    const float* a_w1   = (const float*)d_in[7];
    const float* a_b1   = (const float*)d_in[8];
    const float* a_w2   = (const float*)d_in[9];
    const float* a_b2   = (const float*)d_in[10];
    const float* c_w1   = (const float*)d_in[11];
    const float* c_b1   = (const float*)d_in[12];
    const float* c_w2   = (const float*)d_in[13];
    const float* c_b2   = (const float*)d_in[14];
    float* out = (float*)d_out;

    char* p = (char*)d_ws;
    u16* hb     = (u16*)p;   p += (size_t)NN * HD * 2;     // 25.6 MB
    u16* rstb   = (u16*)p;   p += (size_t)NN * HD * 2;     // 25.6 MB
    u16* pqb    = (u16*)p;   p += (size_t)NN * 128 * 2;    // 12.8 MB
    float* elr  = (float*)p; p += (size_t)NN * 8 * 4;      //  1.6 MB
    float* part = (float*)p; p += 128 * 256 * 4;           // mean partials
    u16* Bsw1   = (u16*)p;   p += 65536;
    u16* Bsw2   = (u16*)p;   p += 65536;
    u16* w2sw   = (u16*)p;   p += 2048;
    int* cnt    = (int*)p;   p += (size_t)NN * 4;          // bucket counters
    u16* bucket = (u16*)p;   p += (size_t)NN * CAP * 2;    //  6.4 MB

    hipMemsetAsync(cnt, 0, (size_t)NN * 4, stream);

    dim3 blk(256);
    // L1: bucket scatter (3125 blocks) + weight swizzle (260 blocks), one launch
    k_scatconv<<<dim3(3125 + 260), blk, 0, stream>>>(src, dst, cnt, bucket,
                                                     fc_w, a_w1, a_w2, Bsw1, Bsw2, w2sw);
    // L2: h = bf16(x @ fc_w) + fused el/er
    gemm1_kernel<<<dim3((NN + 31) / 32), blk, 0, stream>>>(x, Bsw1, attn_l, attn_r, hb, elr);
    // L3: gather-aggregate from buckets (at its EA-interface roofline)
    aggregate_kernel<<<dim3(NN / 4), blk, 0, stream>>>(cnt, bucket, elr, hb, gat_b, rstb);
    // L4: pq = bf16(rst @ [w1_top|w1_bot] + [0|b1])  ||  mean stage 1
    k_g2mean<<<dim3(782 + 128), blk, 0, stream>>>(rstb, Bsw2, a_b1, pqb, part);
    // L5: per-edge actor MLP || mean stage 2 + critic head (fused, one block)
    k_mlpfin<<<dim3(12500 + 1), blk, 0, stream>>>(src, dst, pqb, w2sw, a_b2, out, part,
                                                  c_w1, c_b1, c_w2, c_b2,
                                                  out + (size_t)NE * ACT);
}